// Round 20
// baseline (155.982 us; speedup 1.0000x reference)
//
#include <hip/hip_runtime.h>
#include <math.h>

#define TT 4096
#define DM 512
#define NH 8
#define HD 64
#define WN (DM * DM)   // 262144 elements per weight matrix

typedef float f32x4 __attribute__((ext_vector_type(4)));
typedef _Float16 half8 __attribute__((ext_vector_type(8)));

#define GLD16(gp, lp) __builtin_amdgcn_global_load_lds( \
    (const __attribute__((address_space(1))) void*)(gp), \
    (__attribute__((address_space(3))) void*)(lp), 16, 0, 0)

// Q-row permutation: LDS row rho holds global q-row qperm(rho). Maps MFMA C-rows
// (lg*4+r) onto PV B-frag k-slots (lg*8+j) so P stays in registers.
static __device__ __forceinline__ int qperm(int r) {
    return ((r >> 5) << 5) | (((r >> 2) & 3) << 3) | (((r >> 4) & 1) << 2) | (r & 3);
}

// ---------------------------------------------------------------------------
// Convert the three weight matrices to fp16 (RTN). grid (128, 3), 256 thr.
// ---------------------------------------------------------------------------
__global__ __launch_bounds__(256) void wconv(
    const float* __restrict__ Wq, const float* __restrict__ Wk, const float* __restrict__ Wv,
    unsigned short* __restrict__ Wh)
{
    const int z = blockIdx.y;
    const float* __restrict__ src = (z == 0) ? Wq : (z == 1) ? Wk : Wv;
    const int i = (blockIdx.x * 256 + threadIdx.x) * 8;
    float4 a = *(const float4*)&src[i];
    float4 b = *(const float4*)&src[i + 4];
    float v[8] = {a.x, a.y, a.z, a.w, b.x, b.y, b.z, b.w};
    unsigned int hw[4];
    #pragma unroll
    for (int k = 0; k < 4; ++k) {
        unsigned short h0 = __builtin_bit_cast(unsigned short, (_Float16)v[2 * k]);
        unsigned short h1 = __builtin_bit_cast(unsigned short, (_Float16)v[2 * k + 1]);
        hw[k] = (unsigned int)h0 | ((unsigned int)h1 << 16);
    }
    uint4 hv = {hw[0], hw[1], hw[2], hw[3]};
    *(uint4*)&Wh[(size_t)z * WN + i] = hv;
}

// ---------------------------------------------------------------------------
// Projection, 128x128 tile, single-term fp16 MFMA: Y = X*Wh + bias.
// grid (M/128, 512/128, 3), 256 thr (4 waves, each 64x64 out), BK=64.
//   z=0: Q -> fp16 (Qh), pre-scaled 0.125*log2(e)  [exp2 domain]
//   z=1: K -> fp16 (Kh)
//   z=2: V -> fp16, transposed [b][h][d][T] (2 heads per block)
// ---------------------------------------------------------------------------
__global__ __launch_bounds__(256, 3) void proj_mfma(
    const float* __restrict__ X,
    const unsigned short* __restrict__ Whg,
    const float* __restrict__ bq, const float* __restrict__ bk, const float* __restrict__ bv,
    unsigned short* __restrict__ Qh, unsigned short* __restrict__ Kh,
    unsigned short* __restrict__ Vt)
{
    const int z = blockIdx.z;
    const int m0 = blockIdx.x * 128;
    const int n0 = blockIdx.y * 128;
    const int tid = threadIdx.x;
    const int wid = tid >> 6, lane = tid & 63;
    const int lg = lane >> 4, lr = lane & 15;
    const int wr = (wid >> 1) * 64;      // wave row origin (m)
    const int wc = (wid & 1) * 64;       // wave col origin (n)

    __shared__ __attribute__((aligned(16))) unsigned short smem[128 * 72 + 128 * 64];
    auto Xs  = (unsigned short(*)[72])(smem);                 // [128][72]
    unsigned short* Ws0 = smem + 128 * 72;                    // Wh linear [128][64] swz

    const unsigned short* __restrict__ Wh = Whg + (size_t)z * WN;

    f32x4 acc[4][4];
    #pragma unroll
    for (int mt = 0; mt < 4; ++mt)
        #pragma unroll
        for (int nt = 0; nt < 4; ++nt) acc[mt][nt] = (f32x4){0.f, 0.f, 0.f, 0.f};

    const int xr = tid >> 1;
    const int xc = (tid & 1) * 32;

    for (int k0 = 0; k0 < DM; k0 += 64) {
        // stage X (fp32 -> fp16), 32 elems/thread, vector write
        #pragma unroll
        for (int w = 0; w < 4; ++w) {
            float4 fa = *(const float4*)&X[(size_t)(m0 + xr) * DM + k0 + xc + w * 8];
            float4 fb = *(const float4*)&X[(size_t)(m0 + xr) * DM + k0 + xc + w * 8 + 4];
            float v[8] = {fa.x, fa.y, fa.z, fa.w, fb.x, fb.y, fb.z, fb.w};
            unsigned int hw[4];
            #pragma unroll
            for (int k = 0; k < 4; ++k) {
                unsigned short h0 = __builtin_bit_cast(unsigned short, (_Float16)v[2 * k]);
                unsigned short h1 = __builtin_bit_cast(unsigned short, (_Float16)v[2 * k + 1]);
                hw[k] = (unsigned int)h0 | ((unsigned int)h1 << 16);
            }
            uint4 hv = {hw[0], hw[1], hw[2], hw[3]};
            *(uint4*)&Xs[xr][xc + w * 8] = hv;
        }
        // stage Wh via global_load_lds, swizzled source, linear dest
        #pragma unroll
        for (int it = 0; it < 4; ++it) {
            int gi = it * 256 + tid;          // 0..1023
            int fr = gi >> 3;                 // 0..127
            int c  = (gi & 7) ^ (fr & 7);     // inverse swizzle on source
            int dst = (it * 256 + wid * 64) * 16;
            GLD16(&Wh[(size_t)(n0 + fr) * DM + k0 + c * 8], (char*)Ws0 + dst);
        }
        __syncthreads();

        __builtin_amdgcn_s_setprio(1);
        #pragma unroll
        for (int kc = 0; kc < 2; ++kc) {
            half8 xa[4];
            #pragma unroll
            for (int mt = 0; mt < 4; ++mt)
                xa[mt] = __builtin_bit_cast(half8, *(const int4*)&Xs[wr + mt * 16 + lr][kc * 32 + lg * 8]);
            #pragma unroll
            for (int nt = 0; nt < 4; ++nt) {
                int row = wc + nt * 16 + lr;
                int so = row * 128 + ((kc * 4 + lg) ^ (row & 7)) * 16;
                half8 wh = __builtin_bit_cast(half8, *(const int4*)((const char*)Ws0 + so));
                #pragma unroll
                for (int mt = 0; mt < 4; ++mt)
                    acc[mt][nt] = __builtin_amdgcn_mfma_f32_16x16x32_f16(xa[mt], wh, acc[mt][nt], 0, 0, 0);
            }
        }
        __builtin_amdgcn_s_setprio(0);
        __syncthreads();
    }

    if (z < 2) {
        const float* __restrict__ bias = (z == 0) ? bq : bk;
        unsigned short* __restrict__ Dst = (z == 0) ? Qh : Kh;
        const float sc = (z == 0) ? 0.18033688f : 1.0f;   // 0.125 * log2(e)
        #pragma unroll
        for (int nt = 0; nt < 4; ++nt) {
            int n = n0 + wc + nt * 16 + lr;
            float bv_ = bias[n];
            #pragma unroll
            for (int mt = 0; mt < 4; ++mt)
                #pragma unroll
                for (int r = 0; r < 4; ++r) {
                    int m = m0 + wr + mt * 16 + lg * 4 + r;
                    float y = (acc[mt][nt][r] + bv_) * sc;
                    Dst[(size_t)m * DM + n] =
                        __builtin_bit_cast(unsigned short, (_Float16)y);
                }
        }
    } else {
        // V: fp16, bounce through LDS, write transposed [b][h][d][T]
        unsigned short* Tk = (unsigned short*)smem;   // [128][136] u16 = 34.8KB
        #pragma unroll
        for (int nt = 0; nt < 4; ++nt) {
            int d = wc + nt * 16 + lr;               // 0..127 within block
            float bv_ = bv[n0 + d];
            #pragma unroll
            for (int mt = 0; mt < 4; ++mt)
                #pragma unroll
                for (int r = 0; r < 4; ++r) {
                    int t = wr + mt * 16 + lg * 4 + r;   // 0..127
                    float y = acc[mt][nt][r] + bv_;
                    Tk[d * 136 + t] = __builtin_bit_cast(unsigned short, (_Float16)y);
                }
        }
        __syncthreads();
        const int dl = tid >> 1, tq = tid & 1;       // dl 0..127, two 64-t chunks
        const int bb = m0 >> 12, t0 = m0 & (TT - 1);
        const int hh = (n0 >> 6) + (dl >> 6);
        const int d = dl & 63;
        size_t obase = ((size_t)((bb * NH + hh) * HD + d)) * TT + t0 + tq * 64;
        #pragma unroll
        for (int j = 0; j < 8; ++j) {
            uint4 wv = *(const uint4*)&Tk[dl * 136 + tq * 64 + j * 8];
            *(uint4*)&Vt[obase + j * 8] = wv;
        }
    }
}

// ---------------------------------------------------------------------------
// Flash attention, fp16, single-term QK, bias-folded defer-max softmax +
// l-via-MFMA. 64 KROWS/WAVE (rt=4): halves total LDS-read traffic (each
// wave's staged Q/V reads serve 2x the output rows). 2-wave blocks (128 thr),
// 128 krows/block, grid 512, LDS 64KB -> 2 blocks/CU (4 waves/CU; intra-wave
// QK(sB)||SMPV(sA) pipeline carries latency hiding).
// ---------------------------------------------------------------------------
__global__ __launch_bounds__(128, 1) void attn_mfma(
    const unsigned short* __restrict__ Qh, const unsigned short* __restrict__ Kh,
    const unsigned short* __restrict__ Vt,
    float* __restrict__ Out)
{
    const int flat = blockIdx.x;
    const int bh = flat & 15;                 // XCD-grouping: same bh -> same XCD
    const int r0 = (flat >> 4) * 128;
    const int b = bh >> 3, h = bh & 7;
    const int tid = threadIdx.x;
    const int wid = tid >> 6, lane = tid & 63;
    const int lg = lane >> 4, lr = lane & 15;
    const int wr0 = r0 + wid * 64;            // 64 krows per wave

    __shared__ __attribute__((aligned(16))) unsigned short Qs[2][2][64][64]; // [buf][pass][perm q][d]
    __shared__ __attribute__((aligned(16))) unsigned short Vs[2][2][64][64]; // [buf][pass][d][q]

    const size_t qbase = (size_t)b * TT * DM + h * HD;
    const size_t vbase = ((size_t)(b * NH + h)) * HD * TT;

    // K fragments resident in registers: [rowtile 0..3][kc], single fp16
    half8 kf[4][2];
    #pragma unroll
    for (int rt = 0; rt < 4; ++rt)
        #pragma unroll
        for (int kc = 0; kc < 2; ++kc) {
            size_t g = qbase + (size_t)(wr0 + rt * 16 + lr) * DM + kc * 32 + lg * 8;
            kf[rt][kc] = __builtin_bit_cast(half8, *(const int4*)&Kh[g]);
        }

    // ones A-fragment: A[0][k] = 1 -> row 0 of the PV-shaped mfma accumulates
    // sum_q P[q][krow] (the softmax denominator).
    half8 ones;
    {
        _Float16 o = (_Float16)((lr == 0) ? 1.0f : 0.0f);
        #pragma unroll
        for (int j = 0; j < 8; ++j) ones[j] = o;
    }

    // fixed staging pointers (128 threads x 4 iterations cover 512 chunks)
    const unsigned short* qp[4];
    const unsigned short* vp[4];
    int slds[4];
    #pragma unroll
    for (int it = 0; it < 4; ++it) {
        int gi = it * 128 + tid;      // 0..511
        int fr = gi >> 3;             // 0..63
        int ch = (gi & 7) ^ (fr & 7);
        qp[it] = Qh + qbase + (size_t)qperm(fr) * DM + ch * 8;
        vp[it] = Vt + vbase + (size_t)fr * TT + ch * 8;
        slds[it] = (it * 128 + wid * 64) * 16;
    }

    // stage one 128-q step (2 sub-tiles) into buffer bufi
    auto STAGE = [&](int bufi, int q0) {
        #pragma unroll
        for (int tau = 0; tau < 2; ++tau) {
            #pragma unroll
            for (int it = 0; it < 4; ++it) {
                GLD16(qp[it] + (size_t)(q0 + tau * 64) * DM,
                      (char*)&Qs[bufi][tau][0][0] + slds[it]);
                GLD16(vp[it] + q0 + tau * 64,
                      (char*)&Vs[bufi][tau][0][0] + slds[it]);
            }
        }
    };

    float m_s[4];          // running max, log2 domain, starts at 0 (defer-from-0)
    f32x4 lacc[4];
    f32x4 oacc[4][4];
    #pragma unroll
    for (int rt = 0; rt < 4; ++rt) {
        m_s[rt] = 0.f;
        lacc[rt] = (f32x4){0.f, 0.f, 0.f, 0.f};
        #pragma unroll
        for (int dt = 0; dt < 4; ++dt) oacc[rt][dt] = (f32x4){0.f, 0.f, 0.f, 0.f};
    }

    // QK: S^T - m via MFMA C-init = -m (bias folded into the matrix pipe)
    auto QK = [&](int cur, int tau, f32x4 (&sacc)[4][4]) {
        #pragma unroll
        for (int rt = 0; rt < 4; ++rt) {
            float mb = -m_s[rt];
            #pragma unroll
            for (int qt = 0; qt < 4; ++qt) sacc[rt][qt] = (f32x4){mb, mb, mb, mb};
        }
        __builtin_amdgcn_s_setprio(1);
        #pragma unroll
        for (int kc = 0; kc < 2; ++kc) {
            #pragma unroll
            for (int qt = 0; qt < 4; ++qt) {
                int row = qt * 16 + lr;
                int so = ((kc * 4 + lg) ^ (row & 7)) * 16;
                half8 qv = __builtin_bit_cast(half8,
                    *(const int4*)((const char*)&Qs[cur][tau][row][0] + so));
                #pragma unroll
                for (int rt = 0; rt < 4; ++rt)
                    sacc[rt][qt] = __builtin_amdgcn_mfma_f32_16x16x32_f16(qv, kf[rt][kc], sacc[rt][qt], 0, 0, 0);
            }
        }
        __builtin_amdgcn_s_setprio(0);
    };

    // SMPV: defer-max softmax (sacc already biased by -m) + PV
    auto SMPV = [&](int cur, int tau, f32x4 (&sacc)[4][4]) {
        unsigned int hp[4][4][2];
        #pragma unroll
        for (int rt = 0; rt < 4; ++rt) {
            float mx = -INFINITY;
            #pragma unroll
            for (int qt = 0; qt < 4; ++qt)
                #pragma unroll
                for (int r = 0; r < 4; ++r) mx = fmaxf(mx, sacc[rt][qt][r]);
            // defer-max: rescale only when biased max exceeds THR=12 (p <= 2^12)
            if (!__all(mx <= 12.0f)) {
                mx = fmaxf(mx, __shfl_xor(mx, 16));
                mx = fmaxf(mx, __shfl_xor(mx, 32));
                float delta = fmaxf(mx, 0.f);
                float al = __builtin_amdgcn_exp2f(-delta);
                m_s[rt] += delta;
                #pragma unroll
                for (int qt = 0; qt < 4; ++qt)
                    #pragma unroll
                    for (int r = 0; r < 4; ++r) sacc[rt][qt][r] -= delta;
                #pragma unroll
                for (int dt = 0; dt < 4; ++dt)
                    #pragma unroll
                    for (int r = 0; r < 4; ++r) oacc[rt][dt][r] *= al;
                #pragma unroll
                for (int r = 0; r < 4; ++r) lacc[rt][r] *= al;
            }
            #pragma unroll
            for (int qt = 0; qt < 4; ++qt)
                #pragma unroll
                for (int r = 0; r < 4; ++r)
                    sacc[rt][qt][r] = __builtin_amdgcn_exp2f(sacc[rt][qt][r]);
            #pragma unroll
            for (int qt = 0; qt < 4; ++qt)
                #pragma unroll
                for (int pp = 0; pp < 2; ++pp)
                    hp[rt][qt][pp] = __builtin_bit_cast(unsigned int,
                        __builtin_amdgcn_cvt_pkrtz(sacc[rt][qt][2 * pp], sacc[rt][qt][2 * pp + 1]));
        }
        __builtin_amdgcn_s_setprio(1);
        #pragma unroll
        for (int c = 0; c < 2; ++c) {
            half8 pf[4];
            #pragma unroll
            for (int rt = 0; rt < 4; ++rt) {
                int4 ph4 = {(int)hp[rt][2 * c][0], (int)hp[rt][2 * c][1],
                            (int)hp[rt][2 * c + 1][0], (int)hp[rt][2 * c + 1][1]};
                pf[rt] = __builtin_bit_cast(half8, ph4);
            }
            // denominator: row-0-ones A frag sums P over q on the MFMA pipe
            #pragma unroll
            for (int rt = 0; rt < 4; ++rt)
                lacc[rt] = __builtin_amdgcn_mfma_f32_16x16x32_f16(ones, pf[rt], lacc[rt], 0, 0, 0);
            #pragma unroll
            for (int dt = 0; dt < 4; ++dt) {
                int row = dt * 16 + lr;
                int so = ((c * 4 + lg) ^ (row & 7)) * 16;
                half8 vh = __builtin_bit_cast(half8,
                    *(const int4*)((const char*)&Vs[cur][tau][row][0] + so));
                #pragma unroll
                for (int rt = 0; rt < 4; ++rt)
                    oacc[rt][dt] = __builtin_amdgcn_mfma_f32_16x16x32_f16(vh, pf[rt], oacc[rt][dt], 0, 0, 0);
            }
        }
        __builtin_amdgcn_s_setprio(0);
    };

    f32x4 sA[4][4], sB[4][4];

    // prologue: stage step 0 into buf 0 (drain exposed once)
    STAGE(0, 0);
    __syncthreads();

    for (int t = 0; t < TT / 128; ++t) {
        const int cur = t & 1;
        // issue next step's loads FIRST — they land during the passes below
        STAGE(cur ^ 1, ((t + 1) * 128) & (TT - 1));

        QK(cur, 0, sA);
        QK(cur, 1, sB); SMPV(cur, 0, sA);
                        SMPV(cur, 1, sB);

        __syncthreads();   // A consumed by both waves; B loads drained
    }

    // epilogue: out[krow][d] = oacc / l ; l sits in lane lr (row 0) of lacc
    #pragma unroll
    for (int rt = 0; rt < 4; ++rt) {
        float lfull = __shfl(lacc[rt][0], lr);
        float inv = __builtin_amdgcn_rcpf(lfull);
        int row = wr0 + rt * 16 + lr;
        #pragma unroll
        for (int dt = 0; dt < 4; ++dt)
            #pragma unroll
            for (int r = 0; r < 4; ++r)
                Out[((size_t)(b * TT + row)) * DM + h * HD + dt * 16 + lg * 4 + r] =
                    oacc[rt][dt][r] * inv;
    }
}

// ---------------------------------------------------------------------------
extern "C" void kernel_launch(void* const* d_in, const int* in_sizes, int n_in,
                              void* d_out, int out_size, void* d_ws, size_t ws_size,
                              hipStream_t stream)
{
    const float* x  = (const float*)d_in[0];
    const float* Wk = (const float*)d_in[1];
    const float* bk = (const float*)d_in[2];
    const float* Wq = (const float*)d_in[3];
    const float* bq = (const float*)d_in[4];
    const float* Wv = (const float*)d_in[5];
    const float* bv = (const float*)d_in[6];
    float* out = (float*)d_out;

    const size_t SZ = (size_t)2 * TT * DM;
    unsigned short* Qh = (unsigned short*)d_ws;
    unsigned short* Kh = Qh + SZ;
    unsigned short* Vt = Kh + SZ;
    unsigned short* Wh = Vt + SZ;      // 3*WN fp16

    wconv<<<dim3(WN / 2048, 3), dim3(256), 0, stream>>>(Wq, Wk, Wv, Wh);

    dim3 pgrid(2 * TT / 128, DM / 128, 3);
    proj_mfma<<<pgrid, dim3(256), 0, stream>>>(x, Wh, bq, bk, bv, Qh, Kh, Vt);

    attn_mfma<<<dim3(512), dim3(128), 0, stream>>>(Qh, Kh, Vt, out);
}

// Round 21
// 119.921 us; speedup vs baseline: 1.3007x; 1.3007x over previous
//
#include <hip/hip_runtime.h>
#include <math.h>

#define TT 4096
#define DM 512
#define NH 8
#define HD 64
#define WN (DM * DM)   // 262144 elements per weight matrix

typedef float f32x4 __attribute__((ext_vector_type(4)));
typedef _Float16 half8 __attribute__((ext_vector_type(8)));

#define GLD16(gp, lp) __builtin_amdgcn_global_load_lds( \
    (const __attribute__((address_space(1))) void*)(gp), \
    (__attribute__((address_space(3))) void*)(lp), 16, 0, 0)

// Q-row permutation: LDS row rho holds global q-row qperm(rho). Maps MFMA C-rows
// (lg*4+r) onto PV B-frag k-slots (lg*8+j) so P stays in registers.
static __device__ __forceinline__ int qperm(int r) {
    return ((r >> 5) << 5) | (((r >> 2) & 3) << 3) | (((r >> 4) & 1) << 2) | (r & 3);
}

// ---------------------------------------------------------------------------
// Convert the three weight matrices to fp16 (RTN). grid (128, 3), 256 thr.
// ---------------------------------------------------------------------------
__global__ __launch_bounds__(256) void wconv(
    const float* __restrict__ Wq, const float* __restrict__ Wk, const float* __restrict__ Wv,
    unsigned short* __restrict__ Wh)
{
    const int z = blockIdx.y;
    const float* __restrict__ src = (z == 0) ? Wq : (z == 1) ? Wk : Wv;
    const int i = (blockIdx.x * 256 + threadIdx.x) * 8;
    float4 a = *(const float4*)&src[i];
    float4 b = *(const float4*)&src[i + 4];
    float v[8] = {a.x, a.y, a.z, a.w, b.x, b.y, b.z, b.w};
    unsigned int hw[4];
    #pragma unroll
    for (int k = 0; k < 4; ++k) {
        unsigned short h0 = __builtin_bit_cast(unsigned short, (_Float16)v[2 * k]);
        unsigned short h1 = __builtin_bit_cast(unsigned short, (_Float16)v[2 * k + 1]);
        hw[k] = (unsigned int)h0 | ((unsigned int)h1 << 16);
    }
    uint4 hv = {hw[0], hw[1], hw[2], hw[3]};
    *(uint4*)&Wh[(size_t)z * WN + i] = hv;
}

// ---------------------------------------------------------------------------
// Projection, 128x128 tile, single-term fp16 MFMA: Y = X*Wh + bias.
// grid (M/128, 512/128, 3), 256 thr (4 waves, each 64x64 out), BK=64.
//   z=0: Q -> fp16 (Qh), pre-scaled 0.125*log2(e)  [exp2 domain]
//   z=1: K -> fp16 (Kh)
//   z=2: V -> fp16, transposed [b][h][d][T] (2 heads per block)
// ---------------------------------------------------------------------------
__global__ __launch_bounds__(256, 3) void proj_mfma(
    const float* __restrict__ X,
    const unsigned short* __restrict__ Whg,
    const float* __restrict__ bq, const float* __restrict__ bk, const float* __restrict__ bv,
    unsigned short* __restrict__ Qh, unsigned short* __restrict__ Kh,
    unsigned short* __restrict__ Vt)
{
    const int z = blockIdx.z;
    const int m0 = blockIdx.x * 128;
    const int n0 = blockIdx.y * 128;
    const int tid = threadIdx.x;
    const int wid = tid >> 6, lane = tid & 63;
    const int lg = lane >> 4, lr = lane & 15;
    const int wr = (wid >> 1) * 64;      // wave row origin (m)
    const int wc = (wid & 1) * 64;       // wave col origin (n)

    __shared__ __attribute__((aligned(16))) unsigned short smem[128 * 72 + 128 * 64];
    auto Xs  = (unsigned short(*)[72])(smem);                 // [128][72]
    unsigned short* Ws0 = smem + 128 * 72;                    // Wh linear [128][64] swz

    const unsigned short* __restrict__ Wh = Whg + (size_t)z * WN;

    f32x4 acc[4][4];
    #pragma unroll
    for (int mt = 0; mt < 4; ++mt)
        #pragma unroll
        for (int nt = 0; nt < 4; ++nt) acc[mt][nt] = (f32x4){0.f, 0.f, 0.f, 0.f};

    const int xr = tid >> 1;
    const int xc = (tid & 1) * 32;

    for (int k0 = 0; k0 < DM; k0 += 64) {
        // stage X (fp32 -> fp16), 32 elems/thread, vector write
        #pragma unroll
        for (int w = 0; w < 4; ++w) {
            float4 fa = *(const float4*)&X[(size_t)(m0 + xr) * DM + k0 + xc + w * 8];
            float4 fb = *(const float4*)&X[(size_t)(m0 + xr) * DM + k0 + xc + w * 8 + 4];
            float v[8] = {fa.x, fa.y, fa.z, fa.w, fb.x, fb.y, fb.z, fb.w};
            unsigned int hw[4];
            #pragma unroll
            for (int k = 0; k < 4; ++k) {
                unsigned short h0 = __builtin_bit_cast(unsigned short, (_Float16)v[2 * k]);
                unsigned short h1 = __builtin_bit_cast(unsigned short, (_Float16)v[2 * k + 1]);
                hw[k] = (unsigned int)h0 | ((unsigned int)h1 << 16);
            }
            uint4 hv = {hw[0], hw[1], hw[2], hw[3]};
            *(uint4*)&Xs[xr][xc + w * 8] = hv;
        }
        // stage Wh via global_load_lds, swizzled source, linear dest
        #pragma unroll
        for (int it = 0; it < 4; ++it) {
            int gi = it * 256 + tid;          // 0..1023
            int fr = gi >> 3;                 // 0..127
            int c  = (gi & 7) ^ (fr & 7);     // inverse swizzle on source
            int dst = (it * 256 + wid * 64) * 16;
            GLD16(&Wh[(size_t)(n0 + fr) * DM + k0 + c * 8], (char*)Ws0 + dst);
        }
        __syncthreads();

        __builtin_amdgcn_s_setprio(1);
        #pragma unroll
        for (int kc = 0; kc < 2; ++kc) {
            half8 xa[4];
            #pragma unroll
            for (int mt = 0; mt < 4; ++mt)
                xa[mt] = __builtin_bit_cast(half8, *(const int4*)&Xs[wr + mt * 16 + lr][kc * 32 + lg * 8]);
            #pragma unroll
            for (int nt = 0; nt < 4; ++nt) {
                int row = wc + nt * 16 + lr;
                int so = row * 128 + ((kc * 4 + lg) ^ (row & 7)) * 16;
                half8 wh = __builtin_bit_cast(half8, *(const int4*)((const char*)Ws0 + so));
                #pragma unroll
                for (int mt = 0; mt < 4; ++mt)
                    acc[mt][nt] = __builtin_amdgcn_mfma_f32_16x16x32_f16(xa[mt], wh, acc[mt][nt], 0, 0, 0);
            }
        }
        __builtin_amdgcn_s_setprio(0);
        __syncthreads();
    }

    if (z < 2) {
        const float* __restrict__ bias = (z == 0) ? bq : bk;
        unsigned short* __restrict__ Dst = (z == 0) ? Qh : Kh;
        const float sc = (z == 0) ? 0.18033688f : 1.0f;   // 0.125 * log2(e)
        #pragma unroll
        for (int nt = 0; nt < 4; ++nt) {
            int n = n0 + wc + nt * 16 + lr;
            float bv_ = bias[n];
            #pragma unroll
            for (int mt = 0; mt < 4; ++mt)
                #pragma unroll
                for (int r = 0; r < 4; ++r) {
                    int m = m0 + wr + mt * 16 + lg * 4 + r;
                    float y = (acc[mt][nt][r] + bv_) * sc;
                    Dst[(size_t)m * DM + n] =
                        __builtin_bit_cast(unsigned short, (_Float16)y);
                }
        }
    } else {
        // V: fp16, bounce through LDS, write transposed [b][h][d][T]
        unsigned short* Tk = (unsigned short*)smem;   // [128][136] u16 = 34.8KB
        #pragma unroll
        for (int nt = 0; nt < 4; ++nt) {
            int d = wc + nt * 16 + lr;               // 0..127 within block
            float bv_ = bv[n0 + d];
            #pragma unroll
            for (int mt = 0; mt < 4; ++mt)
                #pragma unroll
                for (int r = 0; r < 4; ++r) {
                    int t = wr + mt * 16 + lg * 4 + r;   // 0..127
                    float y = acc[mt][nt][r] + bv_;
                    Tk[d * 136 + t] = __builtin_bit_cast(unsigned short, (_Float16)y);
                }
        }
        __syncthreads();
        const int dl = tid >> 1, tq = tid & 1;       // dl 0..127, two 64-t chunks
        const int bb = m0 >> 12, t0 = m0 & (TT - 1);
        const int hh = (n0 >> 6) + (dl >> 6);
        const int d = dl & 63;
        size_t obase = ((size_t)((bb * NH + hh) * HD + d)) * TT + t0 + tq * 64;
        #pragma unroll
        for (int j = 0; j < 8; ++j) {
            uint4 wv = *(const uint4*)&Tk[dl * 136 + tq * 64 + j * 8];
            *(uint4*)&Vt[obase + j * 8] = wv;
        }
    }
}

// ---------------------------------------------------------------------------
// Flash attention, fp16, single-term QK, defer-max softmax with the bias
// FOLDED INTO THE MFMA ACCUMULATOR INIT (sacc starts at -m, so exp2 runs
// directly on the QK output — no per-element subtract). l-via-MFMA.
// Issue-early double-buffered staging. 32 krows/wave, 128 krows/block,
// grid 512. LDS 64KB, 2 blocks/CU.
// ---------------------------------------------------------------------------
__global__ __launch_bounds__(256, 2) void attn_mfma(
    const unsigned short* __restrict__ Qh, const unsigned short* __restrict__ Kh,
    const unsigned short* __restrict__ Vt,
    float* __restrict__ Out)
{
    const int flat = blockIdx.x;
    const int bh = flat & 15;                 // XCD-grouping: same bh -> same XCD
    const int r0 = (flat >> 4) * 128;
    const int b = bh >> 3, h = bh & 7;
    const int tid = threadIdx.x;
    const int wid = tid >> 6, lane = tid & 63;
    const int lg = lane >> 4, lr = lane & 15;
    const int wr0 = r0 + wid * 32;

    __shared__ __attribute__((aligned(16))) unsigned short Qs[2][2][64][64]; // [buf][pass][perm q][d]
    __shared__ __attribute__((aligned(16))) unsigned short Vs[2][2][64][64]; // [buf][pass][d][q]

    const size_t qbase = (size_t)b * TT * DM + h * HD;
    const size_t vbase = ((size_t)(b * NH + h)) * HD * TT;

    // K fragments resident in registers: [rowtile][kc], single fp16
    half8 kf[2][2];
    #pragma unroll
    for (int rt = 0; rt < 2; ++rt)
        #pragma unroll
        for (int kc = 0; kc < 2; ++kc) {
            size_t g = qbase + (size_t)(wr0 + rt * 16 + lr) * DM + kc * 32 + lg * 8;
            kf[rt][kc] = __builtin_bit_cast(half8, *(const int4*)&Kh[g]);
        }

    // ones A-fragment: A[0][k] = 1 -> row 0 of the PV-shaped mfma accumulates
    // sum_q P[q][krow] (the softmax denominator).
    half8 ones;
    {
        _Float16 o = (_Float16)((lr == 0) ? 1.0f : 0.0f);
        #pragma unroll
        for (int j = 0; j < 8; ++j) ones[j] = o;
    }

    // fixed staging pointers (step offset passed explicitly)
    const unsigned short* qp[2];
    const unsigned short* vp[2];
    int slds[2];
    #pragma unroll
    for (int it = 0; it < 2; ++it) {
        int gi = it * 256 + tid;      // 0..511
        int fr = gi >> 3;             // 0..63
        int ch = (gi & 7) ^ (fr & 7);
        qp[it] = Qh + qbase + (size_t)qperm(fr) * DM + ch * 8;
        vp[it] = Vt + vbase + (size_t)fr * TT + ch * 8;
        slds[it] = (it * 256 + wid * 64) * 16;
    }

    // stage one 128-q step (2 sub-tiles) into buffer bufi
    auto STAGE = [&](int bufi, int q0) {
        #pragma unroll
        for (int tau = 0; tau < 2; ++tau) {
            #pragma unroll
            for (int it = 0; it < 2; ++it) {
                GLD16(qp[it] + (size_t)(q0 + tau * 64) * DM,
                      (char*)&Qs[bufi][tau][0][0] + slds[it]);
                GLD16(vp[it] + q0 + tau * 64,
                      (char*)&Vs[bufi][tau][0][0] + slds[it]);
            }
        }
    };

    float m_s[2];          // running max, log2 domain, starts at 0 (defer-from-0)
    f32x4 lacc[2];
    f32x4 oacc[2][4];
    #pragma unroll
    for (int rt = 0; rt < 2; ++rt) {
        m_s[rt] = 0.f;
        lacc[rt] = (f32x4){0.f, 0.f, 0.f, 0.f};
        #pragma unroll
        for (int dt = 0; dt < 4; ++dt) oacc[rt][dt] = (f32x4){0.f, 0.f, 0.f, 0.f};
    }

    // QK: S^T - m via MFMA C-init = -m (bias folded into the matrix pipe)
    auto QK = [&](int cur, int tau, f32x4 (&sacc)[2][4]) {
        #pragma unroll
        for (int rt = 0; rt < 2; ++rt) {
            float mb = -m_s[rt];
            #pragma unroll
            for (int qt = 0; qt < 4; ++qt) sacc[rt][qt] = (f32x4){mb, mb, mb, mb};
        }
        __builtin_amdgcn_s_setprio(1);
        #pragma unroll
        for (int kc = 0; kc < 2; ++kc) {
            #pragma unroll
            for (int qt = 0; qt < 4; ++qt) {
                int row = qt * 16 + lr;
                int so = ((kc * 4 + lg) ^ (row & 7)) * 16;
                half8 qv = __builtin_bit_cast(half8,
                    *(const int4*)((const char*)&Qs[cur][tau][row][0] + so));
                #pragma unroll
                for (int rt = 0; rt < 2; ++rt)
                    sacc[rt][qt] = __builtin_amdgcn_mfma_f32_16x16x32_f16(qv, kf[rt][kc], sacc[rt][qt], 0, 0, 0);
            }
        }
        __builtin_amdgcn_s_setprio(0);
    };

    // SMPV: defer-max softmax (sacc already biased by -m) + PV
    auto SMPV = [&](int cur, int tau, f32x4 (&sacc)[2][4]) {
        unsigned int hp[2][4][2];
        #pragma unroll
        for (int rt = 0; rt < 2; ++rt) {
            float mx = -INFINITY;
            #pragma unroll
            for (int qt = 0; qt < 4; ++qt)
                #pragma unroll
                for (int r = 0; r < 4; ++r) mx = fmaxf(mx, sacc[rt][qt][r]);
            // defer-max: rescale only when biased max exceeds THR=12 (p <= 2^12)
            if (!__all(mx <= 12.0f)) {
                mx = fmaxf(mx, __shfl_xor(mx, 16));
                mx = fmaxf(mx, __shfl_xor(mx, 32));
                float delta = fmaxf(mx, 0.f);
                float al = __builtin_amdgcn_exp2f(-delta);
                m_s[rt] += delta;
                #pragma unroll
                for (int qt = 0; qt < 4; ++qt)
                    #pragma unroll
                    for (int r = 0; r < 4; ++r) sacc[rt][qt][r] -= delta;
                #pragma unroll
                for (int dt = 0; dt < 4; ++dt)
                    #pragma unroll
                    for (int r = 0; r < 4; ++r) oacc[rt][dt][r] *= al;
                #pragma unroll
                for (int r = 0; r < 4; ++r) lacc[rt][r] *= al;
            }
            #pragma unroll
            for (int qt = 0; qt < 4; ++qt)
                #pragma unroll
                for (int r = 0; r < 4; ++r)
                    sacc[rt][qt][r] = __builtin_amdgcn_exp2f(sacc[rt][qt][r]);
            #pragma unroll
            for (int qt = 0; qt < 4; ++qt)
                #pragma unroll
                for (int pp = 0; pp < 2; ++pp)
                    hp[rt][qt][pp] = __builtin_bit_cast(unsigned int,
                        __builtin_amdgcn_cvt_pkrtz(sacc[rt][qt][2 * pp], sacc[rt][qt][2 * pp + 1]));
        }
        __builtin_amdgcn_s_setprio(1);
        #pragma unroll
        for (int c = 0; c < 2; ++c) {
            half8 pf[2];
            #pragma unroll
            for (int rt = 0; rt < 2; ++rt) {
                int4 ph4 = {(int)hp[rt][2 * c][0], (int)hp[rt][2 * c][1],
                            (int)hp[rt][2 * c + 1][0], (int)hp[rt][2 * c + 1][1]};
                pf[rt] = __builtin_bit_cast(half8, ph4);
            }
            // denominator: row-0-ones A frag sums P over q on the MFMA pipe
            #pragma unroll
            for (int rt = 0; rt < 2; ++rt)
                lacc[rt] = __builtin_amdgcn_mfma_f32_16x16x32_f16(ones, pf[rt], lacc[rt], 0, 0, 0);
            #pragma unroll
            for (int dt = 0; dt < 4; ++dt) {
                int row = dt * 16 + lr;
                int so = ((c * 4 + lg) ^ (row & 7)) * 16;
                half8 vh = __builtin_bit_cast(half8,
                    *(const int4*)((const char*)&Vs[cur][tau][row][0] + so));
                #pragma unroll
                for (int rt = 0; rt < 2; ++rt)
                    oacc[rt][dt] = __builtin_amdgcn_mfma_f32_16x16x32_f16(vh, pf[rt], oacc[rt][dt], 0, 0, 0);
            }
        }
        __builtin_amdgcn_s_setprio(0);
    };

    f32x4 sA[2][4], sB[2][4];

    // prologue: stage step 0 into buf 0 (drain exposed once)
    STAGE(0, 0);
    __syncthreads();

    for (int t = 0; t < TT / 128; ++t) {
        const int cur = t & 1;
        // issue next step's loads FIRST — they land during the passes below
        STAGE(cur ^ 1, ((t + 1) * 128) & (TT - 1));

        QK(cur, 0, sA);
        QK(cur, 1, sB); SMPV(cur, 0, sA);
                        SMPV(cur, 1, sB);

        __syncthreads();   // A consumed by all waves; B loads drained
    }

    // epilogue: out[krow][d] = oacc / l ; l sits in lane lr (row 0) of lacc
    #pragma unroll
    for (int rt = 0; rt < 2; ++rt) {
        float lfull = __shfl(lacc[rt][0], lr);
        float inv = __builtin_amdgcn_rcpf(lfull);
        int row = wr0 + rt * 16 + lr;
        #pragma unroll
        for (int dt = 0; dt < 4; ++dt)
            #pragma unroll
            for (int r = 0; r < 4; ++r)
                Out[((size_t)(b * TT + row)) * DM + h * HD + dt * 16 + lg * 4 + r] =
                    oacc[rt][dt][r] * inv;
    }
}

// ---------------------------------------------------------------------------
extern "C" void kernel_launch(void* const* d_in, const int* in_sizes, int n_in,
                              void* d_out, int out_size, void* d_ws, size_t ws_size,
                              hipStream_t stream)
{
    const float* x  = (const float*)d_in[0];
    const float* Wk = (const float*)d_in[1];
    const float* bk = (const float*)d_in[2];
    const float* Wq = (const float*)d_in[3];
    const float* bq = (const float*)d_in[4];
    const float* Wv = (const float*)d_in[5];
    const float* bv = (const float*)d_in[6];
    float* out = (float*)d_out;

    const size_t SZ = (size_t)2 * TT * DM;
    unsigned short* Qh = (unsigned short*)d_ws;
    unsigned short* Kh = Qh + SZ;
    unsigned short* Vt = Kh + SZ;
    unsigned short* Wh = Vt + SZ;      // 3*WN fp16

    wconv<<<dim3(WN / 2048, 3), dim3(256), 0, stream>>>(Wq, Wk, Wv, Wh);

    dim3 pgrid(2 * TT / 128, DM / 128, 3);
    proj_mfma<<<pgrid, dim3(256), 0, stream>>>(x, Wh, bq, bk, bv, Qh, Kh, Vt);

    attn_mfma<<<dim3(512), dim3(256), 0, stream>>>(Qh, Kh, Vt, out);
}